// Round 10
// baseline (157.121 us; speedup 1.0000x reference)
//
#include <hip/hip_runtime.h>
#include <hip/hip_bf16.h>

#define NBANK 32
#define DHEAD 128
#define DMODEL 2048
#define NSLOT 8192   // B*S*K = 2*1024*4
#define NTOK 2048    // B*S
#define XCROWS 1024  // padded rows per bank (cnt ~256±60 for these inputs)
#define CONV_BLOCKS 4096

typedef __attribute__((ext_vector_type(8))) short short8;
typedef __attribute__((ext_vector_type(8))) float float8;
typedef __attribute__((ext_vector_type(4))) float f32x4;

__device__ __forceinline__ unsigned short f2bf(float f) {
    union { __hip_bfloat16 h; unsigned short u; } cvt;
    cvt.h = __float2bfloat16(f);
    return cvt.u;
}
__device__ __forceinline__ float bf2f(unsigned short u) {
    union { float f; unsigned int v; } cvt;
    cvt.v = ((unsigned int)u) << 16;
    return cvt.f;
}

// Fused prep, one dispatch, no atomics anywhere:
//  blocks [0,4096): convert W fp32 -> bf16 fragment-swizzled wfrag
//    wfrag[(((bank*128+mt)*4+kk)*64+lane)*8+v] = W[bank][k][m],
//    m = mt*16+(lane&15), k = kk*32+(lane>>4)*8+v.
//  blocks [4096,4128): block b = bank. Scan all sel, in-LDS prefix-scan ->
//    deterministic lists/counts (replaces memset+bucket), then compact
//    xc[b][pos][:] = bf16(p * x[slot][:]) in the same kernel.
__global__ void prep_kernel(const float* __restrict__ W,
                            unsigned short* __restrict__ wfrag,
                            const int* __restrict__ sel,
                            const float* __restrict__ x,
                            const float* __restrict__ probs,
                            int* __restrict__ counts,
                            int* __restrict__ lists,
                            unsigned short* __restrict__ xc) {
    if (blockIdx.x < CONV_BLOCKS) {
        int t = blockIdx.x * 256 + threadIdx.x;   // (bank,mt,kk,lane)
        int lane = t & 63;
        int kk = (t >> 6) & 3;
        int mt = (t >> 8) & 127;
        int bank = t >> 15;
        int m = mt * 16 + (lane & 15);
        int kbase = kk * 32 + (lane >> 4) * 8;
        const float* src = W + ((size_t)bank * DHEAD + kbase) * DMODEL + m;
        short8 o;
        #pragma unroll
        for (int v = 0; v < 8; ++v)
            o[v] = (short)f2bf(src[v * DMODEL]);
        reinterpret_cast<short8*>(wfrag)[t] = o;
    } else {
        int b = blockIdx.x - CONV_BLOCKS;          // bank 0..31
        int tid = threadIdx.x;
        __shared__ int sc[256];
        // --- count matches in this thread's contiguous chunk of 32 slots ---
        int base0 = tid * 32;
        int c = 0;
        for (int i = 0; i < 32; ++i) c += (sel[base0 + i] == b) ? 1 : 0;
        sc[tid] = c;
        __syncthreads();
        // --- Hillis-Steele inclusive scan over 256 counts ---
        for (int off = 1; off < 256; off <<= 1) {
            int v = (tid >= off) ? sc[tid - off] : 0;
            __syncthreads();
            sc[tid] += v;
            __syncthreads();
        }
        int pos = sc[tid] - c;                     // exclusive prefix
        for (int i = 0; i < 32; ++i) {
            int slot = base0 + i;
            if (sel[slot] == b) lists[b * NSLOT + pos++] = slot;
        }
        if (tid == 255) counts[b] = sc[255];
        __syncthreads();                           // lists visible block-wide
        // --- compact: 4 waves gather/scale/convert this bank's rows ---
        int wv = tid >> 6, lane = tid & 63;
        int cnt = min(sc[255], XCROWS);
        for (int p = wv; p < cnt; p += 4) {
            int slot = lists[b * NSLOT + p];
            float pr = probs[slot];
            float2 v2 = reinterpret_cast<const float2*>(x + (size_t)slot * DHEAD)[lane];
            ushort2 o;
            o.x = f2bf(v2.x * pr);
            o.y = f2bf(v2.y * pr);
            reinterpret_cast<ushort2*>(xc + ((size_t)b * XCROWS + p) * DHEAD)[lane] = o;
        }
    }
}

// Grouped GEMM: grid = (m-blocks=16, banks=32), 256 threads, z=1.
// R9-PROVEN inner structure verbatim: single LDS buffer, two barriers per
// tile, global_load_lds staging (XOR swizzle folded into per-lane GLOBAL
// source; linear LDS dest), slots_lds + slot-indexed proj epilogue.
// Wave owns 32 m-cols (bw[4][2] resident); wfrag read exactly once from HBM.
__global__ __launch_bounds__(256, 4)
void gemm_kernel(const unsigned short* __restrict__ wfrag,
                 const unsigned short* __restrict__ xc,
                 const int* __restrict__ counts,
                 const int* __restrict__ lists,
                 unsigned short* __restrict__ proj) {
    __shared__ __align__(16) unsigned short A_lds[16 * DHEAD]; // 4 KB
    __shared__ int slots_lds[16];

    int tid = threadIdx.x;
    int w = tid >> 6;          // wave 0..3
    int lane = tid & 63;
    int lane_lo = lane & 15;   // MFMA: A row / B col / D col
    int lane_hi = lane >> 4;   // MFMA: k-group / D row-group
    int bank = blockIdx.y;
    int mw = blockIdx.x * 128 + w * 32;  // this wave's 32-col m-slice
    int mt0 = mw >> 4;                   // first 16-col tile index
    int cnt = min(counts[bank], XCROWS);

    // ---- Preload W fragments: 8 coalesced 16B loads per lane ----
    const short8* wf = reinterpret_cast<const short8*>(wfrag);
    short8 bw[4][2];   // [kk][nf]
    #pragma unroll
    for (int nf = 0; nf < 2; ++nf)
        #pragma unroll
        for (int kk = 0; kk < 4; ++kk)
            bw[kk][nf] = wf[((((bank * 128 + mt0 + nf) * 4) + kk) << 6) + lane];

    // Staging source: thread t fetches chunk (j ^ (row&7)) of row (t>>4) so
    // the LINEAR LDS dest (t*16) holds the swizzled layout the ds_read wants.
    int row16 = tid >> 4, j = tid & 15;
    const char* xc_b = reinterpret_cast<const char*>(xc)
                     + ((size_t)bank * XCROWS + row16) * 256
                     + ((j ^ (row16 & 7)) << 4);
    char* lds_b = reinterpret_cast<char*>(A_lds);
    char* lds_dst = lds_b + (w << 10);   // wave-uniform; HW adds lane*16

    for (int rt = 0; rt * 16 < cnt; ++rt) {
        __syncthreads();   // protect previous iter's A_lds/slots_lds readers
        __builtin_amdgcn_global_load_lds(
            (const __attribute__((address_space(1))) void*)(xc_b + (size_t)rt * 4096),
            (__attribute__((address_space(3))) void*)lds_dst, 16, 0, 0);
        if (tid < 16) {
            int ridx = rt * 16 + tid;
            slots_lds[tid] = (ridx < cnt) ? lists[bank * NSLOT + ridx] : -1;
        }
        __syncthreads();   // compiler drains vmcnt/lgkmcnt before barrier

        f32x4 acc0 = {0.f, 0.f, 0.f, 0.f};
        f32x4 acc1 = {0.f, 0.f, 0.f, 0.f};
        #pragma unroll
        for (int kk = 0; kk < 4; ++kk) {
            // A-frag: row = lane&15, k = kk*32 + 8*(lane>>4) + v (16B contiguous)
            int byteoff = lane_lo * 256 +
                          ((kk * 64 + lane_hi * 16) ^ ((lane_lo & 7) << 4));
            short8 a = *reinterpret_cast<const short8*>(lds_b + byteoff);
            acc0 = __builtin_amdgcn_mfma_f32_16x16x32_bf16(a, bw[kk][0], acc0, 0, 0, 0);
            acc1 = __builtin_amdgcn_mfma_f32_16x16x32_bf16(a, bw[kk][1], acc1, 0, 0, 0);
        }

        // Epilogue: D[row][col], col = lane&15, row = 4*(lane>>4)+v.
        #pragma unroll
        for (int v = 0; v < 4; ++v) {
            int row = lane_hi * 4 + v;
            int slot = slots_lds[row];
            if (slot >= 0) {
                unsigned short* pr = proj + (size_t)slot * DMODEL + mw + lane_lo;
                pr[0]  = f2bf(acc0[v]);
                pr[16] = f2bf(acc1[v]);
            }
        }
    }
}

// Merge: out[tok][m] = sum_k proj[tok*4+k][m] + p_k * bias[sel_k][m].
// 2048 blocks x 256 threads; thread owns 8 consecutive m-columns.
__global__ void merge_kernel(const unsigned short* __restrict__ proj,
                             const int* __restrict__ sel,
                             const float* __restrict__ probs,
                             const float* __restrict__ bias,
                             float* __restrict__ out) {
    int tid = threadIdx.x;
    int tok = blockIdx.x;
    float8 acc = {0.f, 0.f, 0.f, 0.f, 0.f, 0.f, 0.f, 0.f};
    #pragma unroll
    for (int k = 0; k < 4; ++k) {
        int slot = tok * 4 + k;
        short8 pr = reinterpret_cast<const short8*>(proj + (size_t)slot * DMODEL)[tid];
        float p = probs[slot];
        int bk = sel[slot];
        float8 bv = reinterpret_cast<const float8*>(bias + (size_t)bk * DMODEL)[tid];
        #pragma unroll
        for (int jj = 0; jj < 8; ++jj)
            acc[jj] += bf2f((unsigned short)pr[jj]) + p * bv[jj];
    }
    reinterpret_cast<float8*>(out + (size_t)tok * DMODEL)[tid] = acc;
}

extern "C" void kernel_launch(void* const* d_in, const int* in_sizes, int n_in,
                              void* d_out, int out_size, void* d_ws, size_t ws_size,
                              hipStream_t stream) {
    const float* x     = (const float*)d_in[0];  // (2,1024,4,128)
    const int*   sel   = (const int*)  d_in[1];  // (2,1024,4)
    const float* probs = (const float*)d_in[2];  // (2,1024,4)
    const float* W     = (const float*)d_in[3];  // (32,128,2048)
    const float* bias  = (const float*)d_in[4];  // (32,2048)
    float* out = (float*)d_out;                  // (2,1024,2048) fp32

    // ws layout (~65.5 MB):
    //   [0,128)          counts (32 ints, written by prep select blocks)
    //   [1024, ~1.05MB)  lists  (32 x 8192 ints)
    //   [3MB, 11MB)      xc     (32 x 1024 x 128 bf16, bank-compacted p*x)
    //   [12MB, ~28.8MB)  wfrag  (32x128x2048 bf16, fragment-swizzled)
    //   [32MB, ~65.6MB)  proj   (8192 x 2048 bf16, slot-indexed)
    char* ws = (char*)d_ws;
    int* counts = (int*)ws;
    int* lists  = (int*)(ws + 1024);
    unsigned short* xc    = (unsigned short*)(ws + (3u  << 20));
    unsigned short* wfrag = (unsigned short*)(ws + (12u << 20));
    unsigned short* proj  = (unsigned short*)(ws + (32u << 20));

    prep_kernel<<<CONV_BLOCKS + 32, 256, 0, stream>>>(W, wfrag, sel, x, probs,
                                                      counts, lists, xc);
    gemm_kernel<<<dim3(16, 32), 256, 0, stream>>>(wfrag, xc, counts, lists, proj);
    merge_kernel<<<2048, 256, 0, stream>>>(proj, sel, probs, bias, out);
}

// Round 11
// 131.125 us; speedup vs baseline: 1.1983x; 1.1983x over previous
//
#include <hip/hip_runtime.h>
#include <hip/hip_bf16.h>

#define NBANK 32
#define DHEAD 128
#define DMODEL 2048
#define NSLOT 8192   // B*S*K = 2*1024*4
#define NTOK 2048    // B*S
#define XCROWS 1024  // padded rows per bank (cnt ~256±60 for these inputs)
#define CONVW_BLOCKS 512   // 32 banks x 4 kk x 4 khi

typedef __attribute__((ext_vector_type(8))) short short8;
typedef __attribute__((ext_vector_type(8))) float float8;
typedef __attribute__((ext_vector_type(4))) float f32x4;

__device__ __forceinline__ unsigned short f2bf(float f) {
    union { __hip_bfloat16 h; unsigned short u; } cvt;
    cvt.h = __float2bfloat16(f);
    return cvt.u;
}
__device__ __forceinline__ float bf2f(unsigned short u) {
    union { float f; unsigned int v; } cvt;
    cvt.v = ((unsigned int)u) << 16;
    return cvt.f;
}

// Fused prep:
//  blocks [0,512): COALESCED convW via LDS transpose. Block (bank,kk,khi)
//    owns 8 full k-rows (k = kk*32+khi*8+v, v<8) x 2048 m.
//    Phase 1: read rows contiguously (float4), cvt bf16, LDS[m][v].
//    Phase 2: ds_read_b128 linear, write fragment-ordered 256B runs:
//    wfrag[(((bank*128+mt)*4+kk)*64 + khi*16 + lo)*8 + v] = bf16 W[k][m],
//    m = mt*16+lo  -- same layout the gemm preload expects (R2-R9 proven).
//  blocks [512,544): bucket slots by bank (R9-verbatim LDS histogram).
__global__ void prep_kernel(const float* __restrict__ W,
                            unsigned short* __restrict__ wfrag,
                            const int* __restrict__ sel,
                            int* __restrict__ counts,
                            int* __restrict__ lists) {
    if (blockIdx.x < CONVW_BLOCKS) {
        __shared__ __align__(16) unsigned short lds_t[2048 * 8]; // [m][v] 32KB
        int b = blockIdx.x;
        int bank = b >> 4;
        int kk = (b >> 2) & 3;
        int khi = b & 3;
        int tid = threadIdx.x;
        const float* src = W + ((size_t)(bank * DHEAD + kk * 32 + khi * 8)) * DMODEL;
        // Phase 1: 4096 float4 reads, fully coalesced (rows are contiguous).
        #pragma unroll
        for (int i = 0; i < 16; ++i) {
            int idx = i * 256 + tid;          // float4 index
            int v = idx >> 9;                 // row 0..7 (512 float4/row)
            int m4 = (idx & 511) << 2;        // first m of this float4
            float4 f = reinterpret_cast<const float4*>(src)[idx];
            lds_t[(m4 + 0) * 8 + v] = f2bf(f.x);
            lds_t[(m4 + 1) * 8 + v] = f2bf(f.y);
            lds_t[(m4 + 2) * 8 + v] = f2bf(f.z);
            lds_t[(m4 + 3) * 8 + v] = f2bf(f.w);
        }
        __syncthreads();
        // Phase 2: linear ds_read_b128, fragment-ordered coalesced writes.
        #pragma unroll
        for (int i = 0; i < 8; ++i) {
            int u = i * 256 + tid;            // u = m = mt*16 + lo, 0..2047
            int mt = u >> 4, lo = u & 15;
            short8 val = *reinterpret_cast<const short8*>(&lds_t[u * 8]);
            size_t soff = ((size_t)((bank * 128 + mt) * 4 + kk) * 64
                           + khi * 16 + lo) * 8;
            *reinterpret_cast<short8*>(wfrag + soff) = val;
        }
    } else {
        __shared__ int lcount[NBANK];
        __shared__ int lbase[NBANK];
        int tid = threadIdx.x;
        int slot = (blockIdx.x - CONVW_BLOCKS) * 256 + tid;
        if (tid < NBANK) lcount[tid] = 0;
        __syncthreads();
        int bank = sel[slot];
        int mypos = atomicAdd(&lcount[bank], 1);
        __syncthreads();
        if (tid < NBANK) lbase[tid] = atomicAdd(&counts[tid], lcount[tid]);
        __syncthreads();
        lists[bank * NSLOT + lbase[bank] + mypos] = slot;
    }
}

// Compact: xc[bank][pos][:] = bf16(p * x[lists[bank][pos]][:]).
// One wave per row; rows beyond cnt stay poisoned (harmless: they feed only
// discarded D rows).
__global__ void compact_kernel(const float* __restrict__ x,
                               const float* __restrict__ probs,
                               const int* __restrict__ counts,
                               const int* __restrict__ lists,
                               unsigned short* __restrict__ xc) {
    int bank = blockIdx.x;
    int wv = (threadIdx.x >> 6) + blockIdx.y * 4;  // 0..15
    int lane = threadIdx.x & 63;
    int cnt = min(counts[bank], XCROWS);
    for (int pos = wv; pos < cnt; pos += 16) {
        int slot = lists[bank * NSLOT + pos];
        float p = probs[slot];
        float2 v = reinterpret_cast<const float2*>(x + (size_t)slot * DHEAD)[lane];
        ushort2 o;
        o.x = f2bf(v.x * p);
        o.y = f2bf(v.y * p);
        reinterpret_cast<ushort2*>(xc + ((size_t)bank * XCROWS + pos) * DHEAD)[lane] = o;
    }
}

// Grouped GEMM: grid = (m-blocks=16, banks=32), 256 threads, z=1.
// R9/R10-PROVEN inner structure: single LDS buffer, two barriers per tile,
// global_load_lds staging (XOR swizzle folded into per-lane GLOBAL source;
// linear LDS dest), slots_lds + slot-indexed proj epilogue. Wave owns 32
// m-cols (bw[4][2] resident); wfrag read exactly once from HBM.
__global__ __launch_bounds__(256, 4)
void gemm_kernel(const unsigned short* __restrict__ wfrag,
                 const unsigned short* __restrict__ xc,
                 const int* __restrict__ counts,
                 const int* __restrict__ lists,
                 unsigned short* __restrict__ proj) {
    __shared__ __align__(16) unsigned short A_lds[16 * DHEAD]; // 4 KB
    __shared__ int slots_lds[16];

    int tid = threadIdx.x;
    int w = tid >> 6;          // wave 0..3
    int lane = tid & 63;
    int lane_lo = lane & 15;   // MFMA: A row / B col / D col
    int lane_hi = lane >> 4;   // MFMA: k-group / D row-group
    int bank = blockIdx.y;
    int mw = blockIdx.x * 128 + w * 32;  // this wave's 32-col m-slice
    int mt0 = mw >> 4;                   // first 16-col tile index
    int cnt = min(counts[bank], XCROWS);

    // ---- Preload W fragments: 8 coalesced 16B loads per lane ----
    const short8* wf = reinterpret_cast<const short8*>(wfrag);
    short8 bw[4][2];   // [kk][nf]
    #pragma unroll
    for (int nf = 0; nf < 2; ++nf)
        #pragma unroll
        for (int kk = 0; kk < 4; ++kk)
            bw[kk][nf] = wf[((((bank * 128 + mt0 + nf) * 4) + kk) << 6) + lane];

    // Staging source: thread t fetches chunk (j ^ (row&7)) of row (t>>4) so
    // the LINEAR LDS dest (t*16) holds the swizzled layout the ds_read wants.
    int row16 = tid >> 4, j = tid & 15;
    const char* xc_b = reinterpret_cast<const char*>(xc)
                     + ((size_t)bank * XCROWS + row16) * 256
                     + ((j ^ (row16 & 7)) << 4);
    char* lds_b = reinterpret_cast<char*>(A_lds);
    char* lds_dst = lds_b + (w << 10);   // wave-uniform; HW adds lane*16

    for (int rt = 0; rt * 16 < cnt; ++rt) {
        __syncthreads();   // protect previous iter's A_lds/slots_lds readers
        __builtin_amdgcn_global_load_lds(
            (const __attribute__((address_space(1))) void*)(xc_b + (size_t)rt * 4096),
            (__attribute__((address_space(3))) void*)lds_dst, 16, 0, 0);
        if (tid < 16) {
            int ridx = rt * 16 + tid;
            slots_lds[tid] = (ridx < cnt) ? lists[bank * NSLOT + ridx] : -1;
        }
        __syncthreads();   // compiler drains vmcnt/lgkmcnt before barrier

        f32x4 acc0 = {0.f, 0.f, 0.f, 0.f};
        f32x4 acc1 = {0.f, 0.f, 0.f, 0.f};
        #pragma unroll
        for (int kk = 0; kk < 4; ++kk) {
            // A-frag: row = lane&15, k = kk*32 + 8*(lane>>4) + v (16B contiguous)
            int byteoff = lane_lo * 256 +
                          ((kk * 64 + lane_hi * 16) ^ ((lane_lo & 7) << 4));
            short8 a = *reinterpret_cast<const short8*>(lds_b + byteoff);
            acc0 = __builtin_amdgcn_mfma_f32_16x16x32_bf16(a, bw[kk][0], acc0, 0, 0, 0);
            acc1 = __builtin_amdgcn_mfma_f32_16x16x32_bf16(a, bw[kk][1], acc1, 0, 0, 0);
        }

        // Epilogue: D[row][col], col = lane&15, row = 4*(lane>>4)+v.
        #pragma unroll
        for (int v = 0; v < 4; ++v) {
            int row = lane_hi * 4 + v;
            int slot = slots_lds[row];
            if (slot >= 0) {
                unsigned short* pr = proj + (size_t)slot * DMODEL + mw + lane_lo;
                pr[0]  = f2bf(acc0[v]);
                pr[16] = f2bf(acc1[v]);
            }
        }
    }
}

// Merge: out[tok][m] = sum_k proj[tok*4+k][m] + p_k * bias[sel_k][m].
// 2048 blocks x 256 threads; thread owns 8 consecutive m-columns.
__global__ void merge_kernel(const unsigned short* __restrict__ proj,
                             const int* __restrict__ sel,
                             const float* __restrict__ probs,
                             const float* __restrict__ bias,
                             float* __restrict__ out) {
    int tid = threadIdx.x;
    int tok = blockIdx.x;
    float8 acc = {0.f, 0.f, 0.f, 0.f, 0.f, 0.f, 0.f, 0.f};
    #pragma unroll
    for (int k = 0; k < 4; ++k) {
        int slot = tok * 4 + k;
        short8 pr = reinterpret_cast<const short8*>(proj + (size_t)slot * DMODEL)[tid];
        float p = probs[slot];
        int bk = sel[slot];
        float8 bv = reinterpret_cast<const float8*>(bias + (size_t)bk * DMODEL)[tid];
        #pragma unroll
        for (int jj = 0; jj < 8; ++jj)
            acc[jj] += bf2f((unsigned short)pr[jj]) + p * bv[jj];
    }
    reinterpret_cast<float8*>(out + (size_t)tok * DMODEL)[tid] = acc;
}

extern "C" void kernel_launch(void* const* d_in, const int* in_sizes, int n_in,
                              void* d_out, int out_size, void* d_ws, size_t ws_size,
                              hipStream_t stream) {
    const float* x     = (const float*)d_in[0];  // (2,1024,4,128)
    const int*   sel   = (const int*)  d_in[1];  // (2,1024,4)
    const float* probs = (const float*)d_in[2];  // (2,1024,4)
    const float* W     = (const float*)d_in[3];  // (32,128,2048)
    const float* bias  = (const float*)d_in[4];  // (32,2048)
    float* out = (float*)d_out;                  // (2,1024,2048) fp32

    // ws layout (~65.5 MB):
    //   [0,128)          counts (32 ints, zeroed each call)
    //   [1024, ~1.05MB)  lists  (32 x 8192 ints)
    //   [3MB, 11MB)      xc     (32 x 1024 x 128 bf16, bank-compacted p*x)
    //   [12MB, ~28.8MB)  wfrag  (32x128x2048 bf16, fragment-swizzled)
    //   [32MB, ~65.6MB)  proj   (8192 x 2048 bf16, slot-indexed)
    char* ws = (char*)d_ws;
    int* counts = (int*)ws;
    int* lists  = (int*)(ws + 1024);
    unsigned short* xc    = (unsigned short*)(ws + (3u  << 20));
    unsigned short* wfrag = (unsigned short*)(ws + (12u << 20));
    unsigned short* proj  = (unsigned short*)(ws + (32u << 20));

    hipMemsetAsync(counts, 0, 128, stream);
    prep_kernel<<<CONVW_BLOCKS + 32, 256, 0, stream>>>(W, wfrag, sel, counts, lists);
    compact_kernel<<<dim3(32, 4), 256, 0, stream>>>(x, probs, counts, lists, xc);
    gemm_kernel<<<dim3(16, 32), 256, 0, stream>>>(wfrag, xc, counts, lists, proj);
    merge_kernel<<<2048, 256, 0, stream>>>(proj, sel, probs, bias, out);
}